// Round 5
// baseline (1732.107 us; speedup 1.0000x reference)
//
#include <hip/hip_runtime.h>
#include <hip/hip_bf16.h>

typedef __attribute__((ext_vector_type(4))) float f32x4;
typedef __attribute__((ext_vector_type(8))) short bf16x8;
typedef unsigned int   u32;
typedef unsigned short u16;

#define D_DIM 2048
#define I_DIM 768
#define NE    64
#define CAP   1024
#define NTOK  4096

__device__ __forceinline__ u32 cvt2(float a, float b) {
  __hip_bfloat162 hh = __float22bfloat162_rn(float2{a, b});
  union { __hip_bfloat162 h; u32 u; } c; c.h = hh; return c.u;
}
__device__ __forceinline__ u16 f2b(float f) {
  __hip_bfloat16 b = __float2bfloat16(f);
  union { __hip_bfloat16 b; u16 u; } c; c.b = b; return c.u;
}
// async global->LDS, 16B per lane. LDS dest = wave-uniform base + lane*16.
__device__ __forceinline__ void glp16(const void* g, void* l) {
  __builtin_amdgcn_global_load_lds(
      (const __attribute__((address_space(1))) u32*)g,
      (__attribute__((address_space(3))) u32*)l, 16, 0, 0);
}

// ---------------- x fp32 -> bf16 ----------------
__global__ __launch_bounds__(256) void k_cvt_x(const float* __restrict__ x,
                                               u16* __restrict__ xb) {
  const size_t i = ((size_t)blockIdx.x * 256 + threadIdx.x) * 8;
  float4 v0 = *(const float4*)(x + i);
  float4 v1 = *(const float4*)(x + i + 4);
  uint4 o;
  o.x = cvt2(v0.x, v0.y); o.y = cvt2(v0.z, v0.w);
  o.z = cvt2(v1.x, v1.y); o.w = cvt2(v1.z, v1.w);
  *(uint4*)(xb + i) = o;
}

// ---------------- fp32 [R][C] -> bf16 [C][R] transpose-convert, per expert ----
// grid (C/64, R/64, E), block 256, 64x64 tiles via LDS.
__global__ __launch_bounds__(256) void k_cvt_t(const float* __restrict__ in,
                                               u16* __restrict__ outp,
                                               int R, int C) {
  const int e  = blockIdx.z;
  const int c0 = blockIdx.x * 64;
  const int r0 = blockIdx.y * 64;
  const float* ip = in + (size_t)e * R * C;
  u16* op = outp + (size_t)e * R * C;

  __shared__ u16 T[64][72];
  const int t  = threadIdx.x;
  const int rr = t >> 4;         // 0..15
  const int cc = (t & 15) * 4;   // 0..60
  #pragma unroll
  for (int it = 0; it < 4; ++it) {
    const int r = rr + it * 16;
    float4 v = *(const float4*)(ip + (size_t)(r0 + r) * C + c0 + cc);
    T[cc + 0][r] = f2b(v.x);
    T[cc + 1][r] = f2b(v.y);
    T[cc + 2][r] = f2b(v.z);
    T[cc + 3][r] = f2b(v.w);
  }
  __syncthreads();
  const int cw = t >> 3;         // 0..31
  const int r8 = (t & 7) * 8;
  #pragma unroll
  for (int jt = 0; jt < 2; ++jt) {
    const int c = cw + jt * 32;
    const u16* s = &T[c][r8];
    uint4 o;
    o.x = (u32)s[0] | ((u32)s[1] << 16);
    o.y = (u32)s[2] | ((u32)s[3] << 16);
    o.z = (u32)s[4] | ((u32)s[5] << 16);
    o.w = (u32)s[6] | ((u32)s[7] << 16);
    *(uint4*)(op + (size_t)(c0 + c) * R + r0 + r8) = o;
  }
}

// ---------------- router: fp32 logits, top-8, renorm, dispatch ----------------
__global__ __launch_bounds__(256) void k_router(
    const float* __restrict__ x, const float* __restrict__ rw,
    int* __restrict__ counts, int* __restrict__ slot_token,
    float* __restrict__ slot_w)
{
  const int lane = threadIdx.x & 63;
  const int tok  = blockIdx.x * 4 + (threadIdx.x >> 6);
  const float* xr = x + (size_t)tok * D_DIM;

  float acc = 0.f;
  for (int d0 = 0; d0 < D_DIM; d0 += 64) {
    float xv = xr[d0 + lane];
    #pragma unroll
    for (int j = 0; j < 64; ++j) {
      float xj = __shfl(xv, j, 64);
      acc = fmaf(xj, rw[(size_t)(d0 + j) * NE + lane], acc);
    }
  }

  float v = acc; int vi = lane;
  float wk[8]; int ei[8];
  float mx0 = 0.f, wsum = 0.f;
  #pragma unroll
  for (int k = 0; k < 8; ++k) {
    float mv = v; int mi = vi;
    #pragma unroll
    for (int off = 32; off >= 1; off >>= 1) {
      float ov = __shfl_xor(mv, off, 64);
      int   oi = __shfl_xor(mi, off, 64);
      if (ov > mv || (ov == mv && oi < mi)) { mv = ov; mi = oi; }
    }
    if (k == 0) mx0 = mv;
    float ew = __expf(mv - mx0);
    wk[k] = ew; ei[k] = mi; wsum += ew;
    if (lane == mi) v = -3.4e38f;
  }

  if (lane == 0) {
    float inv = 1.f / wsum;
    #pragma unroll
    for (int k = 0; k < 8; ++k) {
      int ee   = ei[k];
      int slot = atomicAdd(&counts[ee], 1);
      if (slot < CAP) {
        slot_token[ee * CAP + slot] = tok;
        slot_w[ee * CAP + slot]     = wk[k] * inv;
      }
    }
  }
}

// ================= bf16-weight path (all-glp staging) =================

// gate/up fused GEMM + SwiGLU -> h. grid 6144 XCD-swizzled.
// Tile 128m x 64n, BK=32, 2-buf single-barrier, pure global_load_lds staging.
__global__ __launch_bounds__(256, 4) void k_mlp1(
    const u16* __restrict__ xb, const u16* __restrict__ gT,
    const u16* __restrict__ uT, const int* __restrict__ counts,
    const int* __restrict__ slot_token, u16* __restrict__ h)
{
  const int i   = blockIdx.x;
  const int xcd = i & 7;
  const int p   = i >> 3;
  const int mt  = p & 7;
  const int pe  = p >> 3;
  const int val = pe * 8 + xcd;    // == e*12 + nt
  const int e   = val / 12;
  const int nt  = val % 12;

  int cnt = counts[e]; if (cnt > CAP) cnt = CAP;
  const int m0 = mt * 128;
  if (m0 >= cnt) return;
  const int n0 = nt * 64;

  const int t = threadIdx.x;
  const int lane = t & 63, wv = t >> 6;
  const int li = lane & 15, gq = lane >> 4;
  const int wr = wv >> 1, wc = wv & 1;

  __shared__ u16 As[2][4 * 128 * 8];   // 8 KB/buf
  __shared__ u16 Bg[2][4 * 64 * 8];    // 4 KB/buf
  __shared__ u16 Bu[2][4 * 64 * 8];    // 4 KB/buf -> 32 KB total

  // A: wave wv stages m-half mh, kg pair {kgA, kgA+1}
  const int mh  = wv & 1;
  const int kgA = (wv >> 1) * 2;
  const int tok = slot_token[e * CAP + m0 + mh * 64 + lane];  // dead slots -> 0
  const u16* xrow = xb + (size_t)tok * D_DIM;

  // B: waves 0-1 stage gate, waves 2-3 stage up; kg pair {(wv&1)*2, +1}
  const u16* wTb = ((wv >> 1) ? uT : gT) + (size_t)e * D_DIM * I_DIM
                   + (size_t)(n0 + lane) * D_DIM;
  u16* Bm0 = (wv >> 1) ? &Bu[0][0] : &Bg[0][0];
  u16* Bm1 = (wv >> 1) ? &Bu[1][0] : &Bg[1][0];
  const int kgB = (wv & 1) * 2;

  f32x4 ag[4][2], au[4][2];
  #pragma unroll
  for (int m = 0; m < 4; ++m)
    #pragma unroll
    for (int n = 0; n < 2; ++n) {
      f32x4 z = {0.f, 0.f, 0.f, 0.f};
      ag[m][n] = z; au[m][n] = z;
    }

  // prologue: stage tile 0 into buf 0
  glp16(xrow + kgA * 8,       &As[0][(kgA * 128 + mh * 64) * 8]);
  glp16(xrow + (kgA + 1) * 8, &As[0][((kgA + 1) * 128 + mh * 64) * 8]);
  glp16(wTb + kgB * 8,        Bm0 + (kgB * 64) * 8);
  glp16(wTb + (kgB + 1) * 8,  Bm0 + ((kgB + 1) * 64) * 8);
  __syncthreads();

  int buf = 0;
  for (int kk = 0; kk < D_DIM; kk += 32) {
    if (kk + 32 < D_DIM) {      // issue prefetch of tile t+1 (flies under MFMA)
      const u16* xp = xrow + kk + 32;
      const u16* wp = wTb + kk + 32;
      u16* An = &As[buf ^ 1][0];
      u16* Bn = buf ? Bm0 : Bm1;
      glp16(xp + kgA * 8,       An + (kgA * 128 + mh * 64) * 8);
      glp16(xp + (kgA + 1) * 8, An + ((kgA + 1) * 128 + mh * 64) * 8);
      glp16(wp + kgB * 8,       Bn + (kgB * 64) * 8);
      glp16(wp + (kgB + 1) * 8, Bn + ((kgB + 1) * 64) * 8);
    }

    {
      bf16x8 a0 = *(const bf16x8*)&As[buf][(gq * 128 + wr * 64 +      li) * 8];
      bf16x8 a1 = *(const bf16x8*)&As[buf][(gq * 128 + wr * 64 + 16 + li) * 8];
      bf16x8 a2 = *(const bf16x8*)&As[buf][(gq * 128 + wr * 64 + 32 + li) * 8];
      bf16x8 a3 = *(const bf16x8*)&As[buf][(gq * 128 + wr * 64 + 48 + li) * 8];
      bf16x8 g0 = *(const bf16x8*)&Bg[buf][(gq * 64 + wc * 32 +      li) * 8];
      bf16x8 g1 = *(const bf16x8*)&Bg[buf][(gq * 64 + wc * 32 + 16 + li) * 8];
      bf16x8 u0 = *(const bf16x8*)&Bu[buf][(gq * 64 + wc * 32 +      li) * 8];
      bf16x8 u1 = *(const bf16x8*)&Bu[buf][(gq * 64 + wc * 32 + 16 + li) * 8];
      ag[0][0] = __builtin_amdgcn_mfma_f32_16x16x32_bf16(a0, g0, ag[0][0], 0, 0, 0);
      ag[1][0] = __builtin_amdgcn_mfma_f32_16x16x32_bf16(a1, g0, ag[1][0], 0, 0, 0);
      ag[2][0] = __builtin_amdgcn_mfma_f32_16x16x32_bf16(a2, g0, ag[2][0], 0, 0, 0);
      ag[3][0] = __builtin_amdgcn_mfma_f32_16x16x32_bf16(a3, g0, ag[3][0], 0, 0, 0);
      ag[0][1] = __builtin_amdgcn_mfma_f32_16x16x32_bf16(a0, g1, ag[0][1], 0, 0, 0);
      ag[1][1] = __builtin_amdgcn_mfma_f32_16x16x32_bf16(a1, g1, ag[1][1], 0, 0, 0);
      ag[2][1] = __builtin_amdgcn_mfma_f32_16x16x32_bf16(a2, g1, ag[2][1], 0, 0, 0);
      ag[3][1] = __builtin_amdgcn_mfma_f32_16x16x32_bf16(a3, g1, ag[3][1], 0, 0, 0);
      au[0][0] = __builtin_amdgcn_mfma_f32_16x16x32_bf16(a0, u0, au[0][0], 0, 0, 0);
      au[1][0] = __builtin_amdgcn_mfma_f32_16x16x32_bf16(a1, u0, au[1][0], 0, 0, 0);
      au[2][0] = __builtin_amdgcn_mfma_f32_16x16x32_bf16(a2, u0, au[2][0], 0, 0, 0);
      au[3][0] = __builtin_amdgcn_mfma_f32_16x16x32_bf16(a3, u0, au[3][0], 0, 0, 0);
      au[0][1] = __builtin_amdgcn_mfma_f32_16x16x32_bf16(a0, u1, au[0][1], 0, 0, 0);
      au[1][1] = __builtin_amdgcn_mfma_f32_16x16x32_bf16(a1, u1, au[1][1], 0, 0, 0);
      au[2][1] = __builtin_amdgcn_mfma_f32_16x16x32_bf16(a2, u1, au[2][1], 0, 0, 0);
      au[3][1] = __builtin_amdgcn_mfma_f32_16x16x32_bf16(a3, u1, au[3][1], 0, 0, 0);
    }
    __syncthreads();   // reads(t) done; prefetch(t+1) drained+visible
    buf ^= 1;
  }

  #pragma unroll
  for (int mf = 0; mf < 4; ++mf) {
    #pragma unroll
    for (int j = 0; j < 4; ++j) {
      const int slot = m0 + wr * 64 + mf * 16 + gq * 4 + j;
      u16* hr = h + (size_t)(e * CAP + slot) * I_DIM + n0 + wc * 32 + li;
      #pragma unroll
      for (int nf = 0; nf < 2; ++nf) {
        float gg = ag[mf][nf][j];
        float uu = au[mf][nf][j];
        hr[nf * 16] = f2b(gg * uu / (1.f + __expf(-gg)));
      }
    }
  }
}

// down GEMM + weighted scatter-add. grid 8192 XCD-swizzled.
// Tile 128m x 128n, BK=32, 2-buf single-barrier, pure glp staging.
__global__ __launch_bounds__(256, 4) void k_mlp2(
    const u16* __restrict__ h, const u16* __restrict__ dT,
    const int* __restrict__ counts, const int* __restrict__ slot_token,
    const float* __restrict__ slot_w, float* __restrict__ out)
{
  const int i   = blockIdx.x;
  const int xcd = i & 7;
  const int p   = i >> 3;
  const int mt  = p & 7;
  const int pe  = p >> 3;
  const int val = pe * 8 + xcd;    // == e*16 + nt
  const int e   = val >> 4;
  const int nt  = val & 15;

  int cnt = counts[e]; if (cnt > CAP) cnt = CAP;
  const int m0 = mt * 128;
  if (m0 >= cnt) return;
  const int n0 = nt * 128;

  const int t = threadIdx.x;
  const int lane = t & 63, wv = t >> 6;
  const int li = lane & 15, gq = lane >> 4;
  const int wm = (wv >> 1) * 64, wn = (wv & 1) * 64;

  __shared__ u16 As[2][4 * 128 * 8];   // 8 KB/buf
  __shared__ u16 Bt[2][4 * 128 * 8];   // 8 KB/buf -> 32 KB total

  const int mh  = wv & 1;
  const int kgA = (wv >> 1) * 2;
  const u16* hrow = h + (size_t)(e * CAP + m0 + mh * 64 + lane) * I_DIM;

  // B: wave wv, glp c: kg = (wv>>1)+2c, n-half = wv&1
  const int nh   = wv & 1;
  const int kgB0 = wv >> 1;
  const u16* drow = dT + (size_t)e * I_DIM * D_DIM
                    + (size_t)(n0 + nh * 64 + lane) * I_DIM;

  f32x4 acc[4][4];
  #pragma unroll
  for (int m = 0; m < 4; ++m)
    #pragma unroll
    for (int n = 0; n < 4; ++n) { f32x4 z = {0.f,0.f,0.f,0.f}; acc[m][n] = z; }

  glp16(hrow + kgA * 8,          &As[0][(kgA * 128 + mh * 64) * 8]);
  glp16(hrow + (kgA + 1) * 8,    &As[0][((kgA + 1) * 128 + mh * 64) * 8]);
  glp16(drow + kgB0 * 8,         &Bt[0][(kgB0 * 128 + nh * 64) * 8]);
  glp16(drow + (kgB0 + 2) * 8,   &Bt[0][((kgB0 + 2) * 128 + nh * 64) * 8]);
  __syncthreads();

  int buf = 0;
  for (int kk = 0; kk < I_DIM; kk += 32) {
    if (kk + 32 < I_DIM) {
      const u16* hp = hrow + kk + 32;
      const u16* dp = drow + kk + 32;
      u16* An = &As[buf ^ 1][0];
      u16* Bn = &Bt[buf ^ 1][0];
      glp16(hp + kgA * 8,        An + (kgA * 128 + mh * 64) * 8);
      glp16(hp + (kgA + 1) * 8,  An + ((kgA + 1) * 128 + mh * 64) * 8);
      glp16(dp + kgB0 * 8,       Bn + (kgB0 * 128 + nh * 64) * 8);
      glp16(dp + (kgB0 + 2) * 8, Bn + ((kgB0 + 2) * 128 + nh * 64) * 8);
    }

    {
      bf16x8 a[4], b[4];
      #pragma unroll
      for (int mf = 0; mf < 4; ++mf)
        a[mf] = *(const bf16x8*)&As[buf][(gq * 128 + wm + mf * 16 + li) * 8];
      #pragma unroll
      for (int nf = 0; nf < 4; ++nf)
        b[nf] = *(const bf16x8*)&Bt[buf][(gq * 128 + wn + nf * 16 + li) * 8];
      #pragma unroll
      for (int mf = 0; mf < 4; ++mf)
        #pragma unroll
        for (int nf = 0; nf < 4; ++nf)
          acc[mf][nf] = __builtin_amdgcn_mfma_f32_16x16x32_bf16(a[mf], b[nf], acc[mf][nf], 0, 0, 0);
    }
    __syncthreads();
    buf ^= 1;
  }

  #pragma unroll
  for (int mf = 0; mf < 4; ++mf) {
    #pragma unroll
    for (int j = 0; j < 4; ++j) {
      const int slot = m0 + wm + mf * 16 + gq * 4 + j;
      if (slot < cnt) {
        const int   tk  = slot_token[e * CAP + slot];
        const float wgt = slot_w[e * CAP + slot];
        float* orow = out + (size_t)tk * D_DIM + n0 + wn + li;
        #pragma unroll
        for (int nf = 0; nf < 4; ++nf)
          atomicAdd(&orow[nf * 16], wgt * acc[mf][nf][j]);
      }
    }
  }
}

// ================= fallback path (round-4, fp32 weights) =================

__global__ __launch_bounds__(256, 4) void k_mlp1f(
    const u16* __restrict__ xb, const float* __restrict__ gate,
    const float* __restrict__ up, const int* __restrict__ counts,
    const int* __restrict__ slot_token, u16* __restrict__ h)
{
  const int i   = blockIdx.x;
  const int xcd = i & 7;
  const int p   = i >> 3;
  const int mt  = p & 7;
  const int pe  = p >> 3;
  const int val = pe * 8 + xcd;
  const int e   = val / 12;
  const int nt  = val % 12;

  int cnt = counts[e]; if (cnt > CAP) cnt = CAP;
  const int m0 = mt * 128;
  if (m0 >= cnt) return;
  const int n0 = nt * 64;

  const int t = threadIdx.x;
  const int lane = t & 63, wv = t >> 6;
  const int li = lane & 15, gq = lane >> 4;
  const int wr = wv >> 1, wc = wv & 1;

  __shared__ u16 As[2][4 * 128 * 8];
  __shared__ u16 Bg[2][4 * 64 * 8];
  __shared__ u16 Bu[2][4 * 64 * 8];

  const int mh  = wv & 1;
  const int kgA = (wv >> 1) * 2;
  const int tok = slot_token[e * CAP + m0 + mh * 64 + lane];
  const u16* xrow = xb + (size_t)tok * D_DIM;

  const float* gb = gate + (size_t)e * D_DIM * I_DIM + n0 + lane;
  const float* ub = up   + (size_t)e * D_DIM * I_DIM + n0 + lane;

  f32x4 ag[4][2], au[4][2];
  #pragma unroll
  for (int m = 0; m < 4; ++m)
    #pragma unroll
    for (int n = 0; n < 2; ++n) {
      f32x4 z = {0.f, 0.f, 0.f, 0.f};
      ag[m][n] = z; au[m][n] = z;
    }

  float gv[8], uv[8];
  glp16(xrow + kgA * 8,       &As[0][(kgA * 128 + mh * 64) * 8]);
  glp16(xrow + (kgA + 1) * 8, &As[0][((kgA + 1) * 128 + mh * 64) * 8]);
  #pragma unroll
  for (int j = 0; j < 8; ++j) {
    gv[j] = gb[(size_t)(wv * 8 + j) * I_DIM];
    uv[j] = ub[(size_t)(wv * 8 + j) * I_DIM];
  }
  {
    uint4 og, ou;
    og.x = cvt2(gv[0], gv[1]); og.y = cvt2(gv[2], gv[3]);
    og.z = cvt2(gv[4], gv[5]); og.w = cvt2(gv[6], gv[7]);
    ou.x = cvt2(uv[0], uv[1]); ou.y = cvt2(uv[2], uv[3]);
    ou.z = cvt2(uv[4], uv[5]); ou.w = cvt2(uv[6], uv[7]);
    *(uint4*)&Bg[0][(wv * 64 + lane) * 8] = og;
    *(uint4*)&Bu[0][(wv * 64 + lane) * 8] = ou;
  }
  __syncthreads();

  int buf = 0;
  for (int kk = 0; kk < D_DIM; kk += 32) {
    const bool more = (kk + 32) < D_DIM;
    if (more) {
      glp16(xrow + kk + 32 + kgA * 8,       &As[buf ^ 1][(kgA * 128 + mh * 64) * 8]);
      glp16(xrow + kk + 32 + (kgA + 1) * 8, &As[buf ^ 1][((kgA + 1) * 128 + mh * 64) * 8]);
      #pragma unroll
      for (int j = 0; j < 8; ++j) {
        gv[j] = gb[(size_t)(kk + 32 + wv * 8 + j) * I_DIM];
        uv[j] = ub[(size_t)(kk + 32 + wv * 8 + j) * I_DIM];
      }
    }
    {
      bf16x8 a0 = *(const bf16x8*)&As[buf][(gq * 128 + wr * 64 +      li) * 8];
      bf16x8 a1 = *(const bf16x8*)&As[buf][(gq * 128 + wr * 64 + 16 + li) * 8];
      bf16x8 a2 = *(const bf16x8*)&As[buf][(gq * 128 + wr * 64 + 32 + li) * 8];
      bf16x8 a3 = *(const bf16x8*)&As[buf][(gq * 128 + wr * 64 + 48 + li) * 8];
      bf16x8 g0 = *(const bf16x8*)&Bg[buf][(gq * 64 + wc * 32 +      li) * 8];
      bf16x8 g1 = *(const bf16x8*)&Bg[buf][(gq * 64 + wc * 32 + 16 + li) * 8];
      bf16x8 u0 = *(const bf16x8*)&Bu[buf][(gq * 64 + wc * 32 +      li) * 8];
      bf16x8 u1 = *(const bf16x8*)&Bu[buf][(gq * 64 + wc * 32 + 16 + li) * 8];
      ag[0][0] = __builtin_amdgcn_mfma_f32_16x16x32_bf16(a0, g0, ag[0][0], 0, 0, 0);
      ag[1][0] = __builtin_amdgcn_mfma_f32_16x16x32_bf16(a1, g0, ag[1][0], 0, 0, 0);
      ag[2][0] = __builtin_amdgcn_mfma_f32_16x16x32_bf16(a2, g0, ag[2][0], 0, 0, 0);
      ag[3][0] = __builtin_amdgcn_mfma_f32_16x16x32_bf16(a3, g0, ag[3][0], 0, 0, 0);
      ag[0][1] = __builtin_amdgcn_mfma_f32_16x16x32_bf16(a0, g1, ag[0][1], 0, 0, 0);
      ag[1][1] = __builtin_amdgcn_mfma_f32_16x16x32_bf16(a1, g1, ag[1][1], 0, 0, 0);
      ag[2][1] = __builtin_amdgcn_mfma_f32_16x16x32_bf16(a2, g1, ag[2][1], 0, 0, 0);
      ag[3][1] = __builtin_amdgcn_mfma_f32_16x16x32_bf16(a3, g1, ag[3][1], 0, 0, 0);
      au[0][0] = __builtin_amdgcn_mfma_f32_16x16x32_bf16(a0, u0, au[0][0], 0, 0, 0);
      au[1][0] = __builtin_amdgcn_mfma_f32_16x16x32_bf16(a1, u0, au[1][0], 0, 0, 0);
      au[2][0] = __builtin_amdgcn_mfma_f32_16x16x32_bf16(a2, u0, au[2][0], 0, 0, 0);
      au[3][0] = __builtin_amdgcn_mfma_f32_16x16x32_bf16(a3, u0, au[3][0], 0, 0, 0);
      au[0][1] = __builtin_amdgcn_mfma_f32_16x16x32_bf16(a0, u1, au[0][1], 0, 0, 0);
      au[1][1] = __builtin_amdgcn_mfma_f32_16x16x32_bf16(a1, u1, au[1][1], 0, 0, 0);
      au[2][1] = __builtin_amdgcn_mfma_f32_16x16x32_bf16(a2, u1, au[2][1], 0, 0, 0);
      au[3][1] = __builtin_amdgcn_mfma_f32_16x16x32_bf16(a3, u1, au[3][1], 0, 0, 0);
    }
    if (more) {
      uint4 og, ou;
      og.x = cvt2(gv[0], gv[1]); og.y = cvt2(gv[2], gv[3]);
      og.z = cvt2(gv[4], gv[5]); og.w = cvt2(gv[6], gv[7]);
      ou.x = cvt2(uv[0], uv[1]); ou.y = cvt2(uv[2], uv[3]);
      ou.z = cvt2(uv[4], uv[5]); ou.w = cvt2(uv[6], uv[7]);
      *(uint4*)&Bg[buf ^ 1][(wv * 64 + lane) * 8] = og;
      *(uint4*)&Bu[buf ^ 1][(wv * 64 + lane) * 8] = ou;
    }
    __syncthreads();
    buf ^= 1;
  }

  #pragma unroll
  for (int mf = 0; mf < 4; ++mf) {
    #pragma unroll
    for (int j = 0; j < 4; ++j) {
      const int slot = m0 + wr * 64 + mf * 16 + gq * 4 + j;
      u16* hr = h + (size_t)(e * CAP + slot) * I_DIM + n0 + wc * 32 + li;
      #pragma unroll
      for (int nf = 0; nf < 2; ++nf) {
        float gg = ag[mf][nf][j];
        float uu = au[mf][nf][j];
        hr[nf * 16] = f2b(gg * uu / (1.f + __expf(-gg)));
      }
    }
  }
}

__global__ __launch_bounds__(256, 4) void k_mlp2f(
    const u16* __restrict__ h, const float* __restrict__ down,
    const int* __restrict__ counts, const int* __restrict__ slot_token,
    const float* __restrict__ slot_w, float* __restrict__ out)
{
  const int i   = blockIdx.x;
  const int xcd = i & 7;
  const int p   = i >> 3;
  const int mt  = p & 7;
  const int pe  = p >> 3;
  const int val = pe * 8 + xcd;
  const int e   = val >> 4;
  const int nt  = val & 15;

  int cnt = counts[e]; if (cnt > CAP) cnt = CAP;
  const int m0 = mt * 128;
  if (m0 >= cnt) return;
  const int n0 = nt * 128;

  const int t = threadIdx.x;
  const int lane = t & 63, wv = t >> 6;
  const int li = lane & 15, gq = lane >> 4;
  const int wm = (wv >> 1) * 64, wn = (wv & 1) * 64;

  __shared__ u16 As[2][4 * 128 * 8];
  __shared__ u16 Bt[2][4 * 128 * 8];

  const int mh  = wv & 1;
  const int kgA = (wv >> 1) * 2;
  const u16* hrow = h + (size_t)(e * CAP + m0 + mh * 64 + lane) * I_DIM;

  const int nB  = t & 127;
  const int kgB = (t >> 7) * 2;
  const float* db = down + (size_t)e * I_DIM * D_DIM + n0 + nB;

  f32x4 acc[4][4];
  #pragma unroll
  for (int m = 0; m < 4; ++m)
    #pragma unroll
    for (int n = 0; n < 4; ++n) { f32x4 z = {0.f,0.f,0.f,0.f}; acc[m][n] = z; }

  float dv[2][8];
  glp16(hrow + kgA * 8,       &As[0][(kgA * 128 + mh * 64) * 8]);
  glp16(hrow + (kgA + 1) * 8, &As[0][((kgA + 1) * 128 + mh * 64) * 8]);
  #pragma unroll
  for (int c = 0; c < 2; ++c)
    #pragma unroll
    for (int j = 0; j < 8; ++j)
      dv[c][j] = db[(size_t)((kgB + c) * 8 + j) * D_DIM];
  #pragma unroll
  for (int c = 0; c < 2; ++c) {
    uint4 o;
    o.x = cvt2(dv[c][0], dv[c][1]); o.y = cvt2(dv[c][2], dv[c][3]);
    o.z = cvt2(dv[c][4], dv[c][5]); o.w = cvt2(dv[c][6], dv[c][7]);
    *(uint4*)&Bt[0][((kgB + c) * 128 + nB) * 8] = o;
  }
  __syncthreads();

  int buf = 0;
  for (int kk = 0; kk < I_DIM; kk += 32) {
    const bool more = (kk + 32) < I_DIM;
    if (more) {
      glp16(hrow + kk + 32 + kgA * 8,       &As[buf ^ 1][(kgA * 128 + mh * 64) * 8]);
      glp16(hrow + kk + 32 + (kgA + 1) * 8, &As[buf ^ 1][((kgA + 1) * 128 + mh * 64) * 8]);
      #pragma unroll
      for (int c = 0; c < 2; ++c)
        #pragma unroll
        for (int j = 0; j < 8; ++j)
          dv[c][j] = db[(size_t)(kk + 32 + (kgB + c) * 8 + j) * D_DIM];
    }
    {
      bf16x8 a[4], b[4];
      #pragma unroll
      for (int mf = 0; mf < 4; ++mf)
        a[mf] = *(const bf16x8*)&As[buf][(gq * 128 + wm + mf * 16 + li) * 8];
      #pragma unroll
      for (int nf = 0; nf < 4; ++nf)
        b[nf] = *(const bf16x8*)&Bt[buf][(gq * 128 + wn + nf * 16 + li) * 8];
      #pragma unroll
      for (int mf = 0; mf < 4; ++mf)
        #pragma unroll
        for (int nf = 0; nf < 4; ++nf)
          acc[mf][nf] = __builtin_amdgcn_mfma_f32_16x16x32_bf16(a[mf], b[nf], acc[mf][nf], 0, 0, 0);
    }
    if (more) {
      #pragma unroll
      for (int c = 0; c < 2; ++c) {
        uint4 o;
        o.x = cvt2(dv[c][0], dv[c][1]); o.y = cvt2(dv[c][2], dv[c][3]);
        o.z = cvt2(dv[c][4], dv[c][5]); o.w = cvt2(dv[c][6], dv[c][7]);
        *(uint4*)&Bt[buf ^ 1][((kgB + c) * 128 + nB) * 8] = o;
      }
    }
    __syncthreads();
    buf ^= 1;
  }

  #pragma unroll
  for (int mf = 0; mf < 4; ++mf) {
    #pragma unroll
    for (int j = 0; j < 4; ++j) {
      const int slot = m0 + wm + mf * 16 + gq * 4 + j;
      if (slot < cnt) {
        const int   tk  = slot_token[e * CAP + slot];
        const float wgt = slot_w[e * CAP + slot];
        float* orow = out + (size_t)tk * D_DIM + n0 + wn + li;
        #pragma unroll
        for (int nf = 0; nf < 4; ++nf)
          atomicAdd(&orow[nf * 16], wgt * acc[mf][nf][j]);
      }
    }
  }
}

extern "C" void kernel_launch(void* const* d_in, const int* in_sizes, int n_in,
                              void* d_out, int out_size, void* d_ws, size_t ws_size,
                              hipStream_t stream) {
  const float* x    = (const float*)d_in[0];
  const float* rw   = (const float*)d_in[1];
  const float* gate = (const float*)d_in[2];
  const float* up   = (const float*)d_in[3];
  const float* down = (const float*)d_in[4];
  float* out = (float*)d_out;

  char* ws = (char*)d_ws;
  int*   counts     = (int*)ws;                        // 1 KB pad
  int*   slot_token = (int*)(ws + 1024);               // 256 KB
  float* slot_w     = (float*)(ws + 1024 + 262144);    // 256 KB
  u16*   xb         = (u16*)(ws + 1024 + 524288);      // 16.78 MB
  u16*   h          = (u16*)(ws + 1024 + 524288 + 16777216);  // 100.7 MB
  const size_t base = 1024 + 524288 + 16777216 + 100663296ull;
  const size_t WSLAB = 201326592ull;                   // one bf16 weight slab
  u16* gT = (u16*)(ws + base);
  u16* uT = (u16*)(ws + base + WSLAB);
  u16* dT = (u16*)(ws + base + 2 * WSLAB);
  const bool wb = ws_size >= base + 3 * WSLAB;         // 722 MB needed

  hipMemsetAsync(counts, 0, NE * sizeof(int), stream);
  hipMemsetAsync(slot_token, 0, (size_t)NE * CAP * sizeof(int), stream);
  hipMemsetAsync(out, 0, (size_t)out_size * sizeof(float), stream);

  k_cvt_x <<<dim3((NTOK * D_DIM) / (256 * 8)), 256, 0, stream>>>(x, xb);
  k_router<<<dim3(NTOK / 4),                   256, 0, stream>>>(x, rw, counts, slot_token, slot_w);

  if (wb) {
    k_cvt_t<<<dim3(12, 32, NE), 256, 0, stream>>>(gate, gT, D_DIM, I_DIM);
    k_cvt_t<<<dim3(12, 32, NE), 256, 0, stream>>>(up,   uT, D_DIM, I_DIM);
    k_cvt_t<<<dim3(32, 12, NE), 256, 0, stream>>>(down, dT, I_DIM, D_DIM);
    k_mlp1<<<dim3(6144), 256, 0, stream>>>(xb, gT, uT, counts, slot_token, h);
    k_mlp2<<<dim3(8192), 256, 0, stream>>>(h, dT, counts, slot_token, slot_w, out);
  } else {
    k_mlp1f<<<dim3(6144), 256, 0, stream>>>(xb, gate, up, counts, slot_token, h);
    k_mlp2f<<<dim3(8192), 256, 0, stream>>>(h, down, counts, slot_token, slot_w, out);
  }
}